// Round 7
// baseline (368.358 us; speedup 1.0000x reference)
//
#include <hip/hip_runtime.h>
#include <hip/hip_bf16.h>
#include <cstdint>

#define D_MODEL 1024
#define NHEADS 16
#define DHEAD 64
#define DMLP 4096
#define BATCH 2
#define SEQ 2048
#define ROWS (BATCH*SEQ)
#define LN_EPS 1e-5f

typedef __attribute__((ext_vector_type(8))) short short8;
typedef __attribute__((ext_vector_type(4))) float f32x4;

typedef const __attribute__((address_space(1))) uint32_t* gas_ptr;
typedef __attribute__((address_space(3))) uint32_t* las_ptr;

__device__ __forceinline__ short f2bf(float f) {
  union { float f; uint32_t u; } v; v.f = f;
  uint32_t r = v.u + 0x7FFFu + ((v.u >> 16) & 1u);
  return (short)(r >> 16);
}
__device__ __forceinline__ float bf2f(short s) {
  union { uint32_t u; float f; } v; v.u = ((uint32_t)(uint16_t)s) << 16;
  return v.f;
}

// ---------------- LayerNorm ----------------
__global__ void ln_kernel(const float* __restrict__ x, const float* __restrict__ w,
                          const float* __restrict__ b, short* __restrict__ out) {
  int row = blockIdx.x;
  int t = threadIdx.x;
  const float4 v = ((const float4*)(x + (size_t)row * D_MODEL))[t];
  float s = v.x + v.y + v.z + v.w;
  float s2 = v.x*v.x + v.y*v.y + v.z*v.z + v.w*v.w;
#pragma unroll
  for (int k = 1; k < 64; k <<= 1) { s += __shfl_xor(s, k); s2 += __shfl_xor(s2, k); }
  __shared__ float red[8];
  int wv = t >> 6;
  if ((t & 63) == 0) { red[wv] = s; red[wv + 4] = s2; }
  __syncthreads();
  s = red[0] + red[1] + red[2] + red[3];
  s2 = red[4] + red[5] + red[6] + red[7];
  float mu = s * (1.0f / D_MODEL);
  float var = s2 * (1.0f / D_MODEL) - mu * mu;
  float rstd = rsqrtf(var + LN_EPS);
  const float4 wv4 = ((const float4*)w)[t];
  const float4 bv4 = ((const float4*)b)[t];
  short4 o4;
  o4.x = f2bf((v.x - mu) * rstd * wv4.x + bv4.x);
  o4.y = f2bf((v.y - mu) * rstd * wv4.y + bv4.y);
  o4.z = f2bf((v.z - mu) * rstd * wv4.z + bv4.z);
  o4.w = f2bf((v.w - mu) * rstd * wv4.w + bv4.w);
  *(short4*)(out + (size_t)row * D_MODEL + t * 4) = o4;
}

// ---------------- Tiled transpose+convert ----------------
__global__ __launch_bounds__(256) void transpose_tile(const float* __restrict__ src, short* __restrict__ dst,
                                                      int R, int C, int srcMatStride) {
  __shared__ float tile[64][65];
  const int m = blockIdx.z;
  const int r0 = blockIdx.y * 64, c0 = blockIdx.x * 64;
  const int tx = threadIdx.x & 15, ty = threadIdx.x >> 4;
  const float* s = src + (size_t)m * srcMatStride + (size_t)r0 * C + c0;
#pragma unroll
  for (int i = 0; i < 4; i++) {
    float4 v = *(const float4*)(s + (size_t)(ty + i * 16) * C + tx * 4);
    tile[ty + i * 16][tx * 4 + 0] = v.x;
    tile[ty + i * 16][tx * 4 + 1] = v.y;
    tile[ty + i * 16][tx * 4 + 2] = v.z;
    tile[ty + i * 16][tx * 4 + 3] = v.w;
  }
  __syncthreads();
  short* d = dst + (size_t)m * C * R + (size_t)c0 * R + r0;
#pragma unroll
  for (int p = 0; p < 4; p++) {
    int c = ty + p * 16;
    int r4 = tx * 4;
    short4 o;
    o.x = f2bf(tile[r4 + 0][c]);
    o.y = f2bf(tile[r4 + 1][c]);
    o.z = f2bf(tile[r4 + 2][c]);
    o.w = f2bf(tile[r4 + 3][c]);
    *(short4*)(d + (size_t)c * R + r4) = o;
  }
}

// ---------------- 256x256 2-phase GEMM, BK=64, 8 waves ----------------
// LDS 128KB dynamic: buf b at b*65536; A tile [256 rows][8 slots x 16B] at +0,
// B tile at +32768. Slot sp of row gr holds source k-chunk sp^(gr&7)
// (pre-swizzled global source, linear gload_lds dest). Read: slot
// (kc*4+l4)^(l15&7) -> 2 lanes/bank = free.
// One vmcnt(0)+s_barrier per K-tile; the 256^2 tile's ~2500cyc MFMA phase
// covers the load latency at depth-1 (the 128^2 kernel's phase could not).
// EPI 0: bf16 store   EPI 2: bias+GELU->bf16
// EPI 3: split-K z: z0 -> outf = v+bias+resid ; z1..3 -> pp1..3
template<int EPI>
__global__ __launch_bounds__(512) void gemm256(const short* __restrict__ A, const short* __restrict__ BT,
    const float* __restrict__ bias, const float* __restrict__ resid,
    float* __restrict__ outf, short* __restrict__ outb,
    float* __restrict__ pp1, float* __restrict__ pp2, float* __restrict__ pp3,
    int M, int N, int K, int LDA, int LDB) {
  extern __shared__ __align__(16) char lds[];
  const int t = threadIdx.x;
  const int l = t & 63, w = t >> 6;
  const int l15 = l & 15, l4 = l >> 4;
  const int row0 = blockIdx.y * 256, col0 = blockIdx.x * 256;
  const int z = blockIdx.z;
  const size_t kz = (size_t)z * K;
  const int wrr = (w >> 2) * 128;     // wave row base
  const int wc = (w & 3) * 64;        // wave col base

  f32x4 acc[8][4] = {};

  auto stage = [&](int ti, int buf) {
    char* b0 = lds + buf * 65536;
    const size_t ko = kz + (size_t)ti * 64;
#pragma unroll
    for (int i = 0; i < 4; i++) {
      int G = (i * 8 + w) * 64 + l;
      int gr = G >> 3, sp = G & 7;
      const short* src = A + (size_t)(row0 + gr) * LDA + ko + ((sp ^ (gr & 7)) * 8);
      __builtin_amdgcn_global_load_lds((gas_ptr)src, (las_ptr)(b0 + G * 16), 16, 0, 0);
    }
#pragma unroll
    for (int i = 0; i < 4; i++) {
      int G = (i * 8 + w) * 64 + l;
      int gr = G >> 3, sp = G & 7;
      const short* src = BT + (size_t)(col0 + gr) * LDB + ko + ((sp ^ (gr & 7)) * 8);
      __builtin_amdgcn_global_load_lds((gas_ptr)src, (las_ptr)(b0 + 32768 + G * 16), 16, 0, 0);
    }
  };

  stage(0, 0);
  asm volatile("s_waitcnt vmcnt(0)" ::: "memory");
  __builtin_amdgcn_s_barrier();

  const int rs0 = ((l4) ^ (l15 & 7)) * 16;       // kc=0 slot byte
  const int rs1 = ((4 + l4) ^ (l15 & 7)) * 16;   // kc=1 slot byte
  const int nk = K >> 6;

  for (int ti = 0; ti < nk; ti++) {
    const int cur = ti & 1;
    if (ti + 1 < nk) stage(ti + 1, cur ^ 1);
    const char* Ab = lds + cur * 65536;
    const char* Bb = Ab + 32768;
    short8 af[8], bfr[4];
    // kc = 0
#pragma unroll
    for (int fr = 0; fr < 8; fr++) af[fr] = *(const short8*)(Ab + (wrr + fr * 16 + l15) * 128 + rs0);
#pragma unroll
    for (int n = 0; n < 4; n++) bfr[n] = *(const short8*)(Bb + (wc + n * 16 + l15) * 128 + rs0);
    __builtin_amdgcn_s_setprio(1);
#pragma unroll
    for (int fr = 0; fr < 8; fr++)
#pragma unroll
      for (int n = 0; n < 4; n++)
        acc[fr][n] = __builtin_amdgcn_mfma_f32_16x16x32_bf16(af[fr], bfr[n], acc[fr][n], 0, 0, 0);
    __builtin_amdgcn_s_setprio(0);
    // kc = 1
#pragma unroll
    for (int fr = 0; fr < 8; fr++) af[fr] = *(const short8*)(Ab + (wrr + fr * 16 + l15) * 128 + rs1);
#pragma unroll
    for (int n = 0; n < 4; n++) bfr[n] = *(const short8*)(Bb + (wc + n * 16 + l15) * 128 + rs1);
    __builtin_amdgcn_s_setprio(1);
#pragma unroll
    for (int fr = 0; fr < 8; fr++)
#pragma unroll
      for (int n = 0; n < 4; n++)
        acc[fr][n] = __builtin_amdgcn_mfma_f32_16x16x32_bf16(af[fr], bfr[n], acc[fr][n], 0, 0, 0);
    __builtin_amdgcn_s_setprio(0);
    if (ti + 1 < nk) { asm volatile("s_waitcnt vmcnt(0)" ::: "memory"); }
    __builtin_amdgcn_s_barrier();
  }

  // epilogue: D[row][col], row=l4*4+j, col=l15 per 16x16 fragment
#pragma unroll
  for (int fr = 0; fr < 8; fr++) {
#pragma unroll
    for (int fc = 0; fc < 4; fc++) {
#pragma unroll
      for (int j = 0; j < 4; j++) {
        int R = row0 + wrr + fr * 16 + l4 * 4 + j;
        int C = col0 + wc + fc * 16 + l15;
        float v = acc[fr][fc][j];
        size_t o = (size_t)R * N + C;
        if (EPI == 0) {
          outb[o] = f2bf(v);
        } else if (EPI == 2) {
          float xx = v + bias[C];
          outb[o] = f2bf(0.5f * xx * (1.0f + erff(xx * 0.70710678118f)));
        } else if (EPI == 3) {
          if (z == 0) outf[o] = v + bias[C] + resid[o];
          else if (z == 1) pp1[o] = v;
          else if (z == 2) pp2[o] = v;
          else pp3[o] = v;
        }
      }
    }
  }
}

// split-K reduces
__global__ void reduce1(float* __restrict__ out, const float* __restrict__ p, int n4) {
  for (int i = blockIdx.x * 256 + threadIdx.x; i < n4; i += gridDim.x * 256) {
    float4 o = ((float4*)out)[i];
    float4 q = ((const float4*)p)[i];
    o.x += q.x; o.y += q.y; o.z += q.z; o.w += q.w;
    ((float4*)out)[i] = o;
  }
}
__global__ void reduce3(float* __restrict__ out, const float* __restrict__ a,
                        const float* __restrict__ b, const float* __restrict__ c, int n4) {
  for (int i = blockIdx.x * 256 + threadIdx.x; i < n4; i += gridDim.x * 256) {
    float4 o = ((float4*)out)[i];
    float4 x = ((const float4*)a)[i];
    float4 y = ((const float4*)b)[i];
    float4 zz = ((const float4*)c)[i];
    o.x += x.x + y.x + zz.x;
    o.y += x.y + y.y + zz.y;
    o.z += x.z + y.z + zz.z;
    o.w += x.w + y.w + zz.w;
    ((float4*)out)[i] = o;
  }
}

// ---------------- 128x128 3-buffer GEMM (kept for WO) ----------------
// EPI 5: split-K over blockIdx.z: z0 -> outf = v (+bias) + resid ; z1 -> part = v
template<int EPI>
__global__ __launch_bounds__(256) void gemm_bt(const short* __restrict__ A, const short* __restrict__ BT,
    const float* __restrict__ bias, const float* __restrict__ resid,
    float* __restrict__ outf, short* __restrict__ outb, float* __restrict__ part,
    int M, int N, int K, int LDA, int LDB) {
  __shared__ alignas(16) short As[3][4096];
  __shared__ alignas(16) short Bs[3][4096];
  const int t = threadIdx.x;
  const int l = t & 63, w = t >> 6;
  const int l15 = l & 15, l4 = l >> 4;
  const int row0 = blockIdx.y * 128, col0 = blockIdx.x * 128;
  if (EPI == 5) {
    A  += (size_t)blockIdx.z * K;
    BT += (size_t)blockIdx.z * K;
  }
  f32x4 acc[4][4] = {};

  const int gr = w * 16 + (l >> 2);
  const int c8 = ((l & 3) ^ ((l >> 3) & 3)) * 8;
  const short* Ab0 = A  + (size_t)(row0 + gr) * LDA + c8;
  const short* Ab1 = A  + (size_t)(row0 + 64 + gr) * LDA + c8;
  const short* Bb0 = BT + (size_t)(col0 + gr) * LDB + c8;
  const short* Bb1 = BT + (size_t)(col0 + 64 + gr) * LDB + c8;
  char* AsB = (char*)As;
  char* BsB = (char*)Bs;
  const int soff = w * 1024 + l * 16;

  auto stg = [&](int ti) {
    const int bo = (ti % 3) * 8192;
    const int k0 = ti << 5;
    __builtin_amdgcn_global_load_lds((gas_ptr)(Ab0 + k0), (las_ptr)(AsB + bo + soff),        16, 0, 0);
    __builtin_amdgcn_global_load_lds((gas_ptr)(Ab1 + k0), (las_ptr)(AsB + bo + 4096 + soff), 16, 0, 0);
    __builtin_amdgcn_global_load_lds((gas_ptr)(Bb0 + k0), (las_ptr)(BsB + bo + soff),        16, 0, 0);
    __builtin_amdgcn_global_load_lds((gas_ptr)(Bb1 + k0), (las_ptr)(BsB + bo + 4096 + soff), 16, 0, 0);
  };

  const int nk = K >> 5;
  stg(0);
  if (nk > 1) stg(1);
  asm volatile("s_waitcnt vmcnt(4)" ::: "memory");
  __builtin_amdgcn_s_barrier();

  const int wr = (w >> 1) * 64, wc = (w & 1) * 64;
  const int rch = (l4 ^ ((l15 >> 1) & 3)) * 16;
  const char* Arow = AsB + (wr >> 6) * 4096 + l15 * 64 + rch;
  const char* Brow = BsB + (wc >> 6) * 4096 + l15 * 64 + rch;

  for (int ti = 0; ti < nk; ti++) {
    const int bo = (ti % 3) * 8192;
    if (ti + 2 < nk) stg(ti + 2);
    short8 a[4], bfr[4];
#pragma unroll
    for (int m = 0; m < 4; m++) a[m]   = *(const short8*)(Arow + bo + m * 1024);
#pragma unroll
    for (int n = 0; n < 4; n++) bfr[n] = *(const short8*)(Brow + bo + n * 1024);
#pragma unroll
    for (int m = 0; m < 4; m++)
#pragma unroll
      for (int n = 0; n < 4; n++)
        acc[m][n] = __builtin_amdgcn_mfma_f32_16x16x32_bf16(a[m], bfr[n], acc[m][n], 0, 0, 0);
    if (ti + 2 < nk)      { asm volatile("s_waitcnt vmcnt(4)" ::: "memory"); }
    else if (ti + 1 < nk) { asm volatile("s_waitcnt vmcnt(0)" ::: "memory"); }
    __builtin_amdgcn_s_barrier();
  }

#pragma unroll
  for (int m = 0; m < 4; m++) {
#pragma unroll
    for (int n = 0; n < 4; n++) {
#pragma unroll
      for (int j = 0; j < 4; j++) {
        int R_ = row0 + wr + m * 16 + l4 * 4 + j;
        int C_ = col0 + wc + n * 16 + l15;
        float v = acc[m][n][j];
        size_t o = (size_t)R_ * N + C_;
        if (EPI == 0) {
          outb[o] = f2bf(v);
        } else if (EPI == 2) {
          float xx = v + bias[C_];
          outb[o] = f2bf(0.5f * xx * (1.0f + erff(xx * 0.70710678118f)));
        } else if (EPI == 5) {
          if (blockIdx.z == 0) outf[o] = v + (bias ? bias[C_] : 0.0f) + resid[o];
          else part[o] = v;
        }
      }
    }
  }
}

// ---------------- MFMA flash attention, 2-phase pipelined ----------------
__device__ __forceinline__ void attn_step(
    int kt_, int qt, int bufP,
    const short* __restrict__ base, const short* __restrict__ vbase,
    short8& vWA, short8& vWB,
    short8& vLA, short8& vLB,
    const short8 qf[2],
    char* KsB, char* VtB, char* PlB,
    f32x4 acc[4], float mrun[4], float lrun[4],
    int w, int l, int q0, int vr, int vd0)
{
  const int l15 = l & 15, l4 = l >> 4;
  const int bufQ = bufP ^ 1;
  if (kt_ < qt) {
#pragma unroll
    for (int i = 0; i < 8; i++) {
      int d = vd0 + i;
      int cs = (vr >> 2) ^ ((d >> 3) & 7);
      uint32_t val = (uint32_t)(uint16_t)vWA[i] | ((uint32_t)(uint16_t)vWB[i] << 16);
      *(uint32_t*)(VtB + bufQ * 9216 + d * 144 + cs * 16 + (vr & 3) * 4) = val;
    }
#pragma unroll
    for (int i = 0; i < 2; i++) {
      int g = (w * 2 + i) * 64 + l;
      int key = g >> 3, ck = g & 7;
      const short* src = base + (size_t)((kt_ + 1) * 64 + key) * 3072 + 1024 + ((ck ^ (key & 7)) * 8);
      __builtin_amdgcn_global_load_lds((gas_ptr)src, (las_ptr)(KsB + bufQ * 8192 + g * 16), 16, 0, 0);
    }
  }
  if (kt_ + 2 <= qt) {
    vLA = *(const short8*)(vbase + (size_t)((kt_ + 2) * 64 + 2 * vr) * 3072);
    vLB = *(const short8*)(vbase + (size_t)((kt_ + 2) * 64 + 2 * vr + 1) * 3072);
  }

  f32x4 sc[4];
#pragma unroll
  for (int cb = 0; cb < 4; cb++) {
    f32x4 s = {};
    int key = cb * 16 + l15;
#pragma unroll
    for (int c = 0; c < 2; c++) {
      int ck = (c * 4 + l4) ^ (key & 7);
      short8 kf = *(const short8*)(KsB + bufP * 8192 + key * 128 + ck * 16);
      s = __builtin_amdgcn_mfma_f32_16x16x32_bf16(qf[c], kf, s, 0, 0, 0);
    }
    sc[cb] = s;
  }

  const bool lastt = (kt_ == qt);
  float alpha[4];
#pragma unroll
  for (int jj = 0; jj < 4; jj++) {
    int qg = q0 + l4 * 4 + jj;
    float s0 = sc[0][jj] * 0.125f;
    float s1 = sc[1][jj] * 0.125f;
    float s2 = sc[2][jj] * 0.125f;
    float s3 = sc[3][jj] * 0.125f;
    if (lastt) {
      int kg = kt_ * 64 + l15;
      if (kg      > qg) s0 = -1e30f;
      if (kg + 16 > qg) s1 = -1e30f;
      if (kg + 32 > qg) s2 = -1e30f;
      if (kg + 48 > qg) s3 = -1e30f;
    }
    float rm = fmaxf(fmaxf(s0, s1), fmaxf(s2, s3));
    rm = fmaxf(rm, __shfl_xor(rm, 1));
    rm = fmaxf(rm, __shfl_xor(rm, 2));
    rm = fmaxf(rm, __shfl_xor(rm, 4));
    rm = fmaxf(rm, __shfl_xor(rm, 8));
    float nm = fmaxf(mrun[jj], rm);
    float al = __expf(mrun[jj] - nm);
    mrun[jj] = nm;
    float p0 = __expf(s0 - nm), p1 = __expf(s1 - nm);
    float p2 = __expf(s2 - nm), p3 = __expf(s3 - nm);
    float ps = p0 + p1 + p2 + p3;
    ps += __shfl_xor(ps, 1);
    ps += __shfl_xor(ps, 2);
    ps += __shfl_xor(ps, 4);
    ps += __shfl_xor(ps, 8);
    lrun[jj] = lrun[jj] * al + ps;
    alpha[jj] = al;
    short* pr = (short*)(PlB + (l4 * 4 + jj) * 144);
    pr[l15]      = f2bf(p0);
    pr[16 + l15] = f2bf(p1);
    pr[32 + l15] = f2bf(p2);
    pr[48 + l15] = f2bf(p3);
  }
#pragma unroll
  for (int db = 0; db < 4; db++) {
    f32x4 a = acc[db];
    a[0] *= alpha[0]; a[1] *= alpha[1]; a[2] *= alpha[2]; a[3] *= alpha[3];
    acc[db] = a;
  }
#pragma unroll
  for (int kc = 0; kc < 2; kc++) {
    short8 pf = *(const short8*)(PlB + l15 * 144 + kc * 64 + l4 * 16);
#pragma unroll
    for (int db = 0; db < 4; db++) {
      int d = db * 16 + l15;
      int cs = (kc * 4 + l4) ^ ((d >> 3) & 7);
      short8 vf = *(const short8*)(VtB + bufP * 9216 + d * 144 + cs * 16);
      acc[db] = __builtin_amdgcn_mfma_f32_16x16x32_bf16(pf, vf, acc[db], 0, 0, 0);
    }
  }
}

__global__ __launch_bounds__(256) void attn_mfma(const short* __restrict__ qkv, short* __restrict__ ctx) {
  __shared__ alignas(16) short Ks[2 * 64 * 64];
  __shared__ alignas(16) short Vt[2 * 64 * 72];
  __shared__ alignas(16) short Pl[4][16 * 72];
  const int t = threadIdx.x;
  const int l = t & 63;
  const int w = t >> 6;
  const int l15 = l & 15, l4 = l >> 4;
  const int bh = blockIdx.x;
  const int b = bh >> 4, h = bh & 15;
  const int qt = (gridDim.y - 1) - blockIdx.y;
  const int q0 = qt * 64 + w * 16;

  const short* base = qkv + (size_t)b * SEQ * 3072 + h * 64;

  short8 qf[2];
#pragma unroll
  for (int c = 0; c < 2; c++)
    qf[c] = *(const short8*)(base + (size_t)(q0 + l15) * 3072 + c * 32 + l4 * 8);

  const int vr = t >> 3;
  const int vd0 = (t & 7) * 8;
  const short* vbase = base + 2048 + vd0;

  char* KsB = (char*)Ks;
  char* VtB = (char*)Vt;
  char* PlB = (char*)&Pl[w][0];

  short8 va0, vb0, va1, vb1;
  va0 = *(const short8*)(vbase + (size_t)(2 * vr) * 3072);
  vb0 = *(const short8*)(vbase + (size_t)(2 * vr + 1) * 3072);
  if (qt >= 1) {
    va1 = *(const short8*)(vbase + (size_t)(64 + 2 * vr) * 3072);
    vb1 = *(const short8*)(vbase + (size_t)(64 + 2 * vr + 1) * 3072);
  }
#pragma unroll
  for (int i = 0; i < 8; i++) {
    int d = vd0 + i;
    int cs = (vr >> 2) ^ ((d >> 3) & 7);
    uint32_t val = (uint32_t)(uint16_t)va0[i] | ((uint32_t)(uint16_t)vb0[i] << 16);
    *(uint32_t*)(VtB + d * 144 + cs * 16 + (vr & 3) * 4) = val;
  }
#pragma unroll
  for (int i = 0; i < 2; i++) {
    int g = (w * 2 + i) * 64 + l;
    int key = g >> 3, ck = g & 7;
    const short* src = base + (size_t)key * 3072 + 1024 + ((ck ^ (key & 7)) * 8);
    __builtin_amdgcn_global_load_lds((gas_ptr)src, (las_ptr)(KsB + g * 16), 16, 0, 0);
  }
  __syncthreads();

  f32x4 acc[4] = {};
  float mrun[4] = {-1e30f, -1e30f, -1e30f, -1e30f};
  float lrun[4] = {0.f, 0.f, 0.f, 0.f};

  int kt = 0;
  while (true) {
    attn_step(kt, qt, 0, base, vbase, va1, vb1, va0, vb0, qf,
              KsB, VtB, PlB, acc, mrun, lrun, w, l, q0, vr, vd0);
    __syncthreads();
    if (++kt > qt) break;
    attn_step(kt, qt, 1, base, vbase, va0, vb0, va1, vb1, qf,
              KsB, VtB, PlB, acc, mrun, lrun, w, l, q0, vr, vd0);
    __syncthreads();
    if (++kt > qt) break;
  }

  float inv[4];
#pragma unroll
  for (int jj = 0; jj < 4; jj++) inv[jj] = 1.0f / lrun[jj];
  short* obase = ctx + (size_t)(b * SEQ + q0) * D_MODEL + h * 64;
#pragma unroll
  for (int db = 0; db < 4; db++)
#pragma unroll
    for (int jj = 0; jj < 4; jj++)
      obase[(size_t)(l4 * 4 + jj) * D_MODEL + db * 16 + l15] = f2bf(acc[db][jj] * inv[jj]);
}

extern "C" void kernel_launch(void* const* d_in, const int* in_sizes, int n_in,
                              void* d_out, int out_size, void* d_ws, size_t ws_size,
                              hipStream_t stream) {
  (void)in_sizes; (void)n_in; (void)out_size; (void)ws_size;
  const float* x    = (const float*)d_in[0];
  const float* WQ   = (const float*)d_in[1];
  const float* WK   = (const float*)d_in[2];
  const float* WV   = (const float*)d_in[3];
  const float* WO   = (const float*)d_in[4];
  const float* W1   = (const float*)d_in[5];
  const float* b1   = (const float*)d_in[6];
  const float* W2   = (const float*)d_in[7];
  const float* b2   = (const float*)d_in[8];
  const float* ln1w = (const float*)d_in[9];
  const float* ln1b = (const float*)d_in[10];
  const float* ln2w = (const float*)d_in[11];
  const float* ln2b = (const float*)d_in[12];
  float* out = (float*)d_out;

  char* p = (char*)d_ws;
  short* h1    = (short*)p; p += (size_t)ROWS * D_MODEL * 2;        // 8 MB
  short* ctx   = (short*)p; p += (size_t)ROWS * D_MODEL * 2;        // 8 MB
  short* h2    = (short*)p; p += (size_t)ROWS * D_MODEL * 2;        // 8 MB
  short* m1    = (short*)p; p += (size_t)ROWS * DMLP * 2;           // 32 MB
  short* wqkvT = (short*)p; p += (size_t)3 * D_MODEL * D_MODEL * 2; // 6 MB
  short* woT   = (short*)p; p += (size_t)D_MODEL * D_MODEL * 2;     // 2 MB
  short* w1T   = (short*)p; p += (size_t)D_MODEL * DMLP * 2;        // 8 MB
  short* w2T   = (short*)p; p += (size_t)D_MODEL * DMLP * 2;        // 8 MB
  short* qkv   = (short*)p; p += (size_t)ROWS * 3 * D_MODEL * 2;    // 24 MB

  // split-K partials (16 MB f32 each) in dead regions:
  float* fp1 = (float*)h1;     // h1+ctx (dead at fc2; WO uses fp2 region instead)
  float* fp2 = (float*)qkv;    // dead after attention
  float* fp3 = (float*)wqkvT;  // wqkvT+woT+w1T (weights consumed; w2T untouched)

  hipFuncSetAttribute((const void*)gemm256<0>, hipFuncAttributeMaxDynamicSharedMemorySize, 131072);
  hipFuncSetAttribute((const void*)gemm256<2>, hipFuncAttributeMaxDynamicSharedMemorySize, 131072);
  hipFuncSetAttribute((const void*)gemm256<3>, hipFuncAttributeMaxDynamicSharedMemorySize, 131072);

  // weight repacks (bf16, B^T layout)
  transpose_tile<<<dim3(1, 16, 16), 256, 0, stream>>>(WQ, wqkvT,                   1024, 64, D_MODEL * DHEAD);
  transpose_tile<<<dim3(1, 16, 16), 256, 0, stream>>>(WK, wqkvT + 1024 * 1024,     1024, 64, D_MODEL * DHEAD);
  transpose_tile<<<dim3(1, 16, 16), 256, 0, stream>>>(WV, wqkvT + 2 * 1024 * 1024, 1024, 64, D_MODEL * DHEAD);
  transpose_tile<<<dim3(16, 16, 1), 256, 0, stream>>>(WO, woT, 1024, 1024, 0);
  transpose_tile<<<dim3(64, 16, 1), 256, 0, stream>>>(W1, w1T, 1024, 4096, 0);
  transpose_tile<<<dim3(16, 64, 1), 256, 0, stream>>>(W2, w2T, 4096, 1024, 0);

  // LN1
  ln_kernel<<<ROWS, 256, 0, stream>>>(x, ln1w, ln1b, h1);
  // QKV projection -> bf16 qkv (256^2 2-phase)
  gemm256<0><<<dim3(3 * D_MODEL / 256, ROWS / 256, 1), 512, 131072, stream>>>(
      h1, wqkvT, nullptr, nullptr, nullptr, qkv, nullptr, nullptr, nullptr,
      ROWS, 3 * D_MODEL, D_MODEL, D_MODEL, D_MODEL);
  // attention
  attn_mfma<<<dim3(BATCH * NHEADS, SEQ / 64), 256, 0, stream>>>(qkv, ctx);
  // output projection, 128^2 split-K z=2: z0 -> out = v + x ; z1 -> fp2
  gemm_bt<5><<<dim3(D_MODEL / 128, ROWS / 128, 2), 256, 0, stream>>>(
      ctx, woT, nullptr, x, out, nullptr, fp2,
      ROWS, D_MODEL, D_MODEL / 2, D_MODEL, D_MODEL);
  reduce1<<<2048, 256, 0, stream>>>(out, fp2, ROWS * D_MODEL / 4);
  // LN2
  ln_kernel<<<ROWS, 256, 0, stream>>>(out, ln2w, ln2b, h2);
  // MLP fc1 + GELU -> bf16 m1 (256^2 2-phase)
  gemm256<2><<<dim3(DMLP / 256, ROWS / 256, 1), 512, 131072, stream>>>(
      h2, w1T, b1, nullptr, nullptr, m1, nullptr, nullptr, nullptr,
      ROWS, DMLP, D_MODEL, D_MODEL, D_MODEL);
  // MLP fc2 (256^2, split-K z=4, K-slices of 1024); z0 fuses bias+resid
  gemm256<3><<<dim3(D_MODEL / 256, ROWS / 256, 4), 512, 131072, stream>>>(
      m1, w2T, b2, out, out, nullptr, fp1, fp2, fp3,
      ROWS, D_MODEL, DMLP / 4, DMLP, DMLP);
  reduce3<<<2048, 256, 0, stream>>>(out, fp1, fp2, fp3, ROWS * D_MODEL / 4);
}

// Round 8
// 314.701 us; speedup vs baseline: 1.1705x; 1.1705x over previous
//
#include <hip/hip_runtime.h>
#include <hip/hip_bf16.h>
#include <cstdint>

#define D_MODEL 1024
#define NHEADS 16
#define DHEAD 64
#define DMLP 4096
#define BATCH 2
#define SEQ 2048
#define ROWS (BATCH*SEQ)
#define LN_EPS 1e-5f

typedef __attribute__((ext_vector_type(8))) short short8;
typedef __attribute__((ext_vector_type(4))) float f32x4;

typedef const __attribute__((address_space(1))) uint32_t* gas_ptr;
typedef __attribute__((address_space(3))) uint32_t* las_ptr;

__device__ __forceinline__ short f2bf(float f) {
  union { float f; uint32_t u; } v; v.f = f;
  uint32_t r = v.u + 0x7FFFu + ((v.u >> 16) & 1u);
  return (short)(r >> 16);
}
__device__ __forceinline__ float bf2f(short s) {
  union { uint32_t u; float f; } v; v.u = ((uint32_t)(uint16_t)s) << 16;
  return v.f;
}

// ---------------- LayerNorm ----------------
__global__ void ln_kernel(const float* __restrict__ x, const float* __restrict__ w,
                          const float* __restrict__ b, short* __restrict__ out) {
  int row = blockIdx.x;
  int t = threadIdx.x;
  const float4 v = ((const float4*)(x + (size_t)row * D_MODEL))[t];
  float s = v.x + v.y + v.z + v.w;
  float s2 = v.x*v.x + v.y*v.y + v.z*v.z + v.w*v.w;
#pragma unroll
  for (int k = 1; k < 64; k <<= 1) { s += __shfl_xor(s, k); s2 += __shfl_xor(s2, k); }
  __shared__ float red[8];
  int wv = t >> 6;
  if ((t & 63) == 0) { red[wv] = s; red[wv + 4] = s2; }
  __syncthreads();
  s = red[0] + red[1] + red[2] + red[3];
  s2 = red[4] + red[5] + red[6] + red[7];
  float mu = s * (1.0f / D_MODEL);
  float var = s2 * (1.0f / D_MODEL) - mu * mu;
  float rstd = rsqrtf(var + LN_EPS);
  const float4 wv4 = ((const float4*)w)[t];
  const float4 bv4 = ((const float4*)b)[t];
  short4 o4;
  o4.x = f2bf((v.x - mu) * rstd * wv4.x + bv4.x);
  o4.y = f2bf((v.y - mu) * rstd * wv4.y + bv4.y);
  o4.z = f2bf((v.z - mu) * rstd * wv4.z + bv4.z);
  o4.w = f2bf((v.w - mu) * rstd * wv4.w + bv4.w);
  *(short4*)(out + (size_t)row * D_MODEL + t * 4) = o4;
}

// ---------------- Tiled transpose+convert ----------------
__global__ __launch_bounds__(256) void transpose_tile(const float* __restrict__ src, short* __restrict__ dst,
                                                      int R, int C, int srcMatStride) {
  __shared__ float tile[64][65];
  const int m = blockIdx.z;
  const int r0 = blockIdx.y * 64, c0 = blockIdx.x * 64;
  const int tx = threadIdx.x & 15, ty = threadIdx.x >> 4;
  const float* s = src + (size_t)m * srcMatStride + (size_t)r0 * C + c0;
#pragma unroll
  for (int i = 0; i < 4; i++) {
    float4 v = *(const float4*)(s + (size_t)(ty + i * 16) * C + tx * 4);
    tile[ty + i * 16][tx * 4 + 0] = v.x;
    tile[ty + i * 16][tx * 4 + 1] = v.y;
    tile[ty + i * 16][tx * 4 + 2] = v.z;
    tile[ty + i * 16][tx * 4 + 3] = v.w;
  }
  __syncthreads();
  short* d = dst + (size_t)m * C * R + (size_t)c0 * R + r0;
#pragma unroll
  for (int p = 0; p < 4; p++) {
    int c = ty + p * 16;
    int r4 = tx * 4;
    short4 o;
    o.x = f2bf(tile[r4 + 0][c]);
    o.y = f2bf(tile[r4 + 1][c]);
    o.z = f2bf(tile[r4 + 2][c]);
    o.w = f2bf(tile[r4 + 3][c]);
    *(short4*)(d + (size_t)c * R + r4) = o;
  }
}

// ---------------- bf16 MFMA GEMM, 128x128 tile, BK=32, B^T input ----------------
// 3-buffer LDS, prefetch depth 2, counted vmcnt(4) + raw s_barrier per K-step.
// XCD N-stripe remap: hardware assigns XCD = dispatch_id % 8; give XCD j a
// contiguous N-stripe (bx in [j*nx/8,(j+1)*nx/8)) so the <=1MB B-stripe stays
// resident in its private 4MB L2, and consecutive per-XCD ids share A-panels.
// EPI 0: bf16 store   EPI 2: bias+GELU->bf16
// EPI 5: split-K over blockIdx.z: z0 -> outf = v (+bias) + resid ; z1 -> part = v
template<int EPI>
__global__ __launch_bounds__(256) void gemm_bt(const short* __restrict__ A, const short* __restrict__ BT,
    const float* __restrict__ bias, const float* __restrict__ resid,
    float* __restrict__ outf, short* __restrict__ outb, float* __restrict__ part,
    int M, int N, int K, int LDA, int LDB) {
  __shared__ alignas(16) short As[3][4096];
  __shared__ alignas(16) short Bs[3][4096];
  const int t = threadIdx.x;
  const int l = t & 63, w = t >> 6;
  const int l15 = l & 15, l4 = l >> 4;

  // XCD N-stripe remap (bijective; requires gridDim.x % 8 == 0, true for all launches)
  const int nx = gridDim.x;
  const int sw = nx >> 3;
  int d = blockIdx.y * nx + blockIdx.x;
  const int xcd = d & 7, li = d >> 3;
  const int bx = xcd * sw + (li % sw);
  const int by = li / sw;
  const int row0 = by * 128, col0 = bx * 128;

  if (EPI == 5) {
    A  += (size_t)blockIdx.z * K;
    BT += (size_t)blockIdx.z * K;
  }
  f32x4 acc[4][4] = {};

  const int gr = w * 16 + (l >> 2);
  const int c8 = ((l & 3) ^ ((l >> 3) & 3)) * 8;
  const short* Ab0 = A  + (size_t)(row0 + gr) * LDA + c8;
  const short* Ab1 = A  + (size_t)(row0 + 64 + gr) * LDA + c8;
  const short* Bb0 = BT + (size_t)(col0 + gr) * LDB + c8;
  const short* Bb1 = BT + (size_t)(col0 + 64 + gr) * LDB + c8;
  char* AsB = (char*)As;
  char* BsB = (char*)Bs;
  const int soff = w * 1024 + l * 16;

  auto stg = [&](int ti) {
    const int bo = (ti % 3) * 8192;
    const int k0 = ti << 5;
    __builtin_amdgcn_global_load_lds((gas_ptr)(Ab0 + k0), (las_ptr)(AsB + bo + soff),        16, 0, 0);
    __builtin_amdgcn_global_load_lds((gas_ptr)(Ab1 + k0), (las_ptr)(AsB + bo + 4096 + soff), 16, 0, 0);
    __builtin_amdgcn_global_load_lds((gas_ptr)(Bb0 + k0), (las_ptr)(BsB + bo + soff),        16, 0, 0);
    __builtin_amdgcn_global_load_lds((gas_ptr)(Bb1 + k0), (las_ptr)(BsB + bo + 4096 + soff), 16, 0, 0);
  };

  const int nk = K >> 5;
  stg(0);
  if (nk > 1) stg(1);
  asm volatile("s_waitcnt vmcnt(4)" ::: "memory");
  __builtin_amdgcn_s_barrier();

  const int wr = (w >> 1) * 64, wc = (w & 1) * 64;
  const int rch = (l4 ^ ((l15 >> 1) & 3)) * 16;
  const char* Arow = AsB + (wr >> 6) * 4096 + l15 * 64 + rch;
  const char* Brow = BsB + (wc >> 6) * 4096 + l15 * 64 + rch;

  for (int ti = 0; ti < nk; ti++) {
    const int bo = (ti % 3) * 8192;
    if (ti + 2 < nk) stg(ti + 2);
    short8 a[4], bfr[4];
#pragma unroll
    for (int m = 0; m < 4; m++) a[m]   = *(const short8*)(Arow + bo + m * 1024);
#pragma unroll
    for (int n = 0; n < 4; n++) bfr[n] = *(const short8*)(Brow + bo + n * 1024);
#pragma unroll
    for (int m = 0; m < 4; m++)
#pragma unroll
      for (int n = 0; n < 4; n++)
        acc[m][n] = __builtin_amdgcn_mfma_f32_16x16x32_bf16(a[m], bfr[n], acc[m][n], 0, 0, 0);
    if (ti + 2 < nk)      { asm volatile("s_waitcnt vmcnt(4)" ::: "memory"); }
    else if (ti + 1 < nk) { asm volatile("s_waitcnt vmcnt(0)" ::: "memory"); }
    __builtin_amdgcn_s_barrier();
  }

#pragma unroll
  for (int m = 0; m < 4; m++) {
#pragma unroll
    for (int n = 0; n < 4; n++) {
#pragma unroll
      for (int j = 0; j < 4; j++) {
        int R_ = row0 + wr + m * 16 + l4 * 4 + j;
        int C_ = col0 + wc + n * 16 + l15;
        float v = acc[m][n][j];
        size_t o = (size_t)R_ * N + C_;
        if (EPI == 0) {
          outb[o] = f2bf(v);
        } else if (EPI == 2) {
          float xx = v + bias[C_];
          outb[o] = f2bf(0.5f * xx * (1.0f + erff(xx * 0.70710678118f)));
        } else if (EPI == 5) {
          if (blockIdx.z == 0) outf[o] = v + (bias ? bias[C_] : 0.0f) + resid[o];
          else part[o] = v;
        }
      }
    }
  }
}

// split-K reduce: out += part
__global__ void reduce1(float* __restrict__ out, const float* __restrict__ p, int n4) {
  for (int i = blockIdx.x * 256 + threadIdx.x; i < n4; i += gridDim.x * 256) {
    float4 o = ((float4*)out)[i];
    float4 q = ((const float4*)p)[i];
    o.x += q.x; o.y += q.y; o.z += q.z; o.w += q.w;
    ((float4*)out)[i] = o;
  }
}

// ---------------- MFMA flash attention, 2-phase pipelined ----------------
__device__ __forceinline__ void attn_step(
    int kt_, int qt, int bufP,
    const short* __restrict__ base, const short* __restrict__ vbase,
    short8& vWA, short8& vWB,
    short8& vLA, short8& vLB,
    const short8 qf[2],
    char* KsB, char* VtB, char* PlB,
    f32x4 acc[4], float mrun[4], float lrun[4],
    int w, int l, int q0, int vr, int vd0)
{
  const int l15 = l & 15, l4 = l >> 4;
  const int bufQ = bufP ^ 1;
  if (kt_ < qt) {
#pragma unroll
    for (int i = 0; i < 8; i++) {
      int d = vd0 + i;
      int cs = (vr >> 2) ^ ((d >> 3) & 7);
      uint32_t val = (uint32_t)(uint16_t)vWA[i] | ((uint32_t)(uint16_t)vWB[i] << 16);
      *(uint32_t*)(VtB + bufQ * 9216 + d * 144 + cs * 16 + (vr & 3) * 4) = val;
    }
#pragma unroll
    for (int i = 0; i < 2; i++) {
      int g = (w * 2 + i) * 64 + l;
      int key = g >> 3, ck = g & 7;
      const short* src = base + (size_t)((kt_ + 1) * 64 + key) * 3072 + 1024 + ((ck ^ (key & 7)) * 8);
      __builtin_amdgcn_global_load_lds((gas_ptr)src, (las_ptr)(KsB + bufQ * 8192 + g * 16), 16, 0, 0);
    }
  }
  if (kt_ + 2 <= qt) {
    vLA = *(const short8*)(vbase + (size_t)((kt_ + 2) * 64 + 2 * vr) * 3072);
    vLB = *(const short8*)(vbase + (size_t)((kt_ + 2) * 64 + 2 * vr + 1) * 3072);
  }

  f32x4 sc[4];
#pragma unroll
  for (int cb = 0; cb < 4; cb++) {
    f32x4 s = {};
    int key = cb * 16 + l15;
#pragma unroll
    for (int c = 0; c < 2; c++) {
      int ck = (c * 4 + l4) ^ (key & 7);
      short8 kf = *(const short8*)(KsB + bufP * 8192 + key * 128 + ck * 16);
      s = __builtin_amdgcn_mfma_f32_16x16x32_bf16(qf[c], kf, s, 0, 0, 0);
    }
    sc[cb] = s;
  }

  const bool lastt = (kt_ == qt);
  float alpha[4];
#pragma unroll
  for (int jj = 0; jj < 4; jj++) {
    int qg = q0 + l4 * 4 + jj;
    float s0 = sc[0][jj] * 0.125f;
    float s1 = sc[1][jj] * 0.125f;
    float s2 = sc[2][jj] * 0.125f;
    float s3 = sc[3][jj] * 0.125f;
    if (lastt) {
      int kg = kt_ * 64 + l15;
      if (kg      > qg) s0 = -1e30f;
      if (kg + 16 > qg) s1 = -1e30f;
      if (kg + 32 > qg) s2 = -1e30f;
      if (kg + 48 > qg) s3 = -1e30f;
    }
    float rm = fmaxf(fmaxf(s0, s1), fmaxf(s2, s3));
    rm = fmaxf(rm, __shfl_xor(rm, 1));
    rm = fmaxf(rm, __shfl_xor(rm, 2));
    rm = fmaxf(rm, __shfl_xor(rm, 4));
    rm = fmaxf(rm, __shfl_xor(rm, 8));
    float nm = fmaxf(mrun[jj], rm);
    float al = __expf(mrun[jj] - nm);
    mrun[jj] = nm;
    float p0 = __expf(s0 - nm), p1 = __expf(s1 - nm);
    float p2 = __expf(s2 - nm), p3 = __expf(s3 - nm);
    float ps = p0 + p1 + p2 + p3;
    ps += __shfl_xor(ps, 1);
    ps += __shfl_xor(ps, 2);
    ps += __shfl_xor(ps, 4);
    ps += __shfl_xor(ps, 8);
    lrun[jj] = lrun[jj] * al + ps;
    alpha[jj] = al;
    short* pr = (short*)(PlB + (l4 * 4 + jj) * 144);
    pr[l15]      = f2bf(p0);
    pr[16 + l15] = f2bf(p1);
    pr[32 + l15] = f2bf(p2);
    pr[48 + l15] = f2bf(p3);
  }
#pragma unroll
  for (int db = 0; db < 4; db++) {
    f32x4 a = acc[db];
    a[0] *= alpha[0]; a[1] *= alpha[1]; a[2] *= alpha[2]; a[3] *= alpha[3];
    acc[db] = a;
  }
#pragma unroll
  for (int kc = 0; kc < 2; kc++) {
    short8 pf = *(const short8*)(PlB + l15 * 144 + kc * 64 + l4 * 16);
#pragma unroll
    for (int db = 0; db < 4; db++) {
      int d = db * 16 + l15;
      int cs = (kc * 4 + l4) ^ ((d >> 3) & 7);
      short8 vf = *(const short8*)(VtB + bufP * 9216 + d * 144 + cs * 16);
      acc[db] = __builtin_amdgcn_mfma_f32_16x16x32_bf16(pf, vf, acc[db], 0, 0, 0);
    }
  }
}

__global__ __launch_bounds__(256) void attn_mfma(const short* __restrict__ qkv, short* __restrict__ ctx) {
  __shared__ alignas(16) short Ks[2 * 64 * 64];
  __shared__ alignas(16) short Vt[2 * 64 * 72];
  __shared__ alignas(16) short Pl[4][16 * 72];
  const int t = threadIdx.x;
  const int l = t & 63;
  const int w = t >> 6;
  const int l15 = l & 15, l4 = l >> 4;
  const int bh = blockIdx.x;
  const int b = bh >> 4, h = bh & 15;
  const int qt = (gridDim.y - 1) - blockIdx.y;
  const int q0 = qt * 64 + w * 16;

  const short* base = qkv + (size_t)b * SEQ * 3072 + h * 64;

  short8 qf[2];
#pragma unroll
  for (int c = 0; c < 2; c++)
    qf[c] = *(const short8*)(base + (size_t)(q0 + l15) * 3072 + c * 32 + l4 * 8);

  const int vr = t >> 3;
  const int vd0 = (t & 7) * 8;
  const short* vbase = base + 2048 + vd0;

  char* KsB = (char*)Ks;
  char* VtB = (char*)Vt;
  char* PlB = (char*)&Pl[w][0];

  short8 va0, vb0, va1, vb1;
  va0 = *(const short8*)(vbase + (size_t)(2 * vr) * 3072);
  vb0 = *(const short8*)(vbase + (size_t)(2 * vr + 1) * 3072);
  if (qt >= 1) {
    va1 = *(const short8*)(vbase + (size_t)(64 + 2 * vr) * 3072);
    vb1 = *(const short8*)(vbase + (size_t)(64 + 2 * vr + 1) * 3072);
  }
#pragma unroll
  for (int i = 0; i < 8; i++) {
    int d = vd0 + i;
    int cs = (vr >> 2) ^ ((d >> 3) & 7);
    uint32_t val = (uint32_t)(uint16_t)va0[i] | ((uint32_t)(uint16_t)vb0[i] << 16);
    *(uint32_t*)(VtB + d * 144 + cs * 16 + (vr & 3) * 4) = val;
  }
#pragma unroll
  for (int i = 0; i < 2; i++) {
    int g = (w * 2 + i) * 64 + l;
    int key = g >> 3, ck = g & 7;
    const short* src = base + (size_t)key * 3072 + 1024 + ((ck ^ (key & 7)) * 8);
    __builtin_amdgcn_global_load_lds((gas_ptr)src, (las_ptr)(KsB + g * 16), 16, 0, 0);
  }
  __syncthreads();

  f32x4 acc[4] = {};
  float mrun[4] = {-1e30f, -1e30f, -1e30f, -1e30f};
  float lrun[4] = {0.f, 0.f, 0.f, 0.f};

  int kt = 0;
  while (true) {
    attn_step(kt, qt, 0, base, vbase, va1, vb1, va0, vb0, qf,
              KsB, VtB, PlB, acc, mrun, lrun, w, l, q0, vr, vd0);
    __syncthreads();
    if (++kt > qt) break;
    attn_step(kt, qt, 1, base, vbase, va0, vb0, va1, vb1, qf,
              KsB, VtB, PlB, acc, mrun, lrun, w, l, q0, vr, vd0);
    __syncthreads();
    if (++kt > qt) break;
  }

  float inv[4];
#pragma unroll
  for (int jj = 0; jj < 4; jj++) inv[jj] = 1.0f / lrun[jj];
  short* obase = ctx + (size_t)(b * SEQ + q0) * D_MODEL + h * 64;
#pragma unroll
  for (int db = 0; db < 4; db++)
#pragma unroll
    for (int jj = 0; jj < 4; jj++)
      obase[(size_t)(l4 * 4 + jj) * D_MODEL + db * 16 + l15] = f2bf(acc[db][jj] * inv[jj]);
}

extern "C" void kernel_launch(void* const* d_in, const int* in_sizes, int n_in,
                              void* d_out, int out_size, void* d_ws, size_t ws_size,
                              hipStream_t stream) {
  (void)in_sizes; (void)n_in; (void)out_size; (void)ws_size;
  const float* x    = (const float*)d_in[0];
  const float* WQ   = (const float*)d_in[1];
  const float* WK   = (const float*)d_in[2];
  const float* WV   = (const float*)d_in[3];
  const float* WO   = (const float*)d_in[4];
  const float* W1   = (const float*)d_in[5];
  const float* b1   = (const float*)d_in[6];
  const float* W2   = (const float*)d_in[7];
  const float* b2   = (const float*)d_in[8];
  const float* ln1w = (const float*)d_in[9];
  const float* ln1b = (const float*)d_in[10];
  const float* ln2w = (const float*)d_in[11];
  const float* ln2b = (const float*)d_in[12];
  float* out = (float*)d_out;

  char* p = (char*)d_ws;
  short* h1    = (short*)p; p += (size_t)ROWS * D_MODEL * 2;        // 8 MB
  short* ctx   = (short*)p; p += (size_t)ROWS * D_MODEL * 2;        // 8 MB
  short* h2    = (short*)p; p += (size_t)ROWS * D_MODEL * 2;        // 8 MB
  short* m1    = (short*)p; p += (size_t)ROWS * DMLP * 2;           // 32 MB
  short* wqkvT = (short*)p; p += (size_t)3 * D_MODEL * D_MODEL * 2; // 6 MB
  short* woT   = (short*)p; p += (size_t)D_MODEL * D_MODEL * 2;     // 2 MB
  short* w1T   = (short*)p; p += (size_t)D_MODEL * DMLP * 2;        // 8 MB
  short* w2T   = (short*)p; p += (size_t)D_MODEL * DMLP * 2;        // 8 MB
  short* qkv   = (short*)p; p += (size_t)ROWS * 3 * D_MODEL * 2;    // 24 MB

  // split-K partial (16 MB f32) in qkv region (dead after attention)
  float* fp1 = (float*)qkv;

  // weight repacks (bf16, B^T layout)
  transpose_tile<<<dim3(1, 16, 16), 256, 0, stream>>>(WQ, wqkvT,                   1024, 64, D_MODEL * DHEAD);
  transpose_tile<<<dim3(1, 16, 16), 256, 0, stream>>>(WK, wqkvT + 1024 * 1024,     1024, 64, D_MODEL * DHEAD);
  transpose_tile<<<dim3(1, 16, 16), 256, 0, stream>>>(WV, wqkvT + 2 * 1024 * 1024, 1024, 64, D_MODEL * DHEAD);
  transpose_tile<<<dim3(16, 16, 1), 256, 0, stream>>>(WO, woT, 1024, 1024, 0);
  transpose_tile<<<dim3(64, 16, 1), 256, 0, stream>>>(W1, w1T, 1024, 4096, 0);
  transpose_tile<<<dim3(16, 64, 1), 256, 0, stream>>>(W2, w2T, 4096, 1024, 0);

  // LN1
  ln_kernel<<<ROWS, 256, 0, stream>>>(x, ln1w, ln1b, h1);
  // QKV projection -> bf16 qkv  (nx=24, XCD stripe = 3 col-tiles)
  gemm_bt<0><<<dim3(3 * D_MODEL / 128, ROWS / 128), 256, 0, stream>>>(
      h1, wqkvT, nullptr, nullptr, nullptr, qkv, nullptr,
      ROWS, 3 * D_MODEL, D_MODEL, D_MODEL, D_MODEL);
  // attention
  attn_mfma<<<dim3(BATCH * NHEADS, SEQ / 64), 256, 0, stream>>>(qkv, ctx);
  // output projection, split-K z=2: z0 -> out = v + x ; z1 -> fp1  (nx=8, stripe=1)
  gemm_bt<5><<<dim3(D_MODEL / 128, ROWS / 128, 2), 256, 0, stream>>>(
      ctx, woT, nullptr, x, out, nullptr, fp1,
      ROWS, D_MODEL, D_MODEL / 2, D_MODEL, D_MODEL);
  reduce1<<<2048, 256, 0, stream>>>(out, fp1, ROWS * D_MODEL / 4);
  // LN2
  ln_kernel<<<ROWS, 256, 0, stream>>>(out, ln2w, ln2b, h2);
  // MLP fc1 + GELU -> bf16 m1  (nx=32, stripe = 4 col-tiles)
  gemm_bt<2><<<dim3(DMLP / 128, ROWS / 128), 256, 0, stream>>>(
      h2, w1T, b1, nullptr, nullptr, m1, nullptr,
      ROWS, DMLP, D_MODEL, D_MODEL, D_MODEL);
  // MLP fc2, split-K z=2: z0 -> out = v + b2 + resid(out) ; z1 -> fp1  (nx=8)
  gemm_bt<5><<<dim3(D_MODEL / 128, ROWS / 128, 2), 256, 0, stream>>>(
      m1, w2T, b2, out, out, nullptr, fp1,
      ROWS, D_MODEL, DMLP / 2, DMLP, DMLP);
  reduce1<<<2048, 256, 0, stream>>>(out, fp1, ROWS * D_MODEL / 4);
}